// Round 6
// baseline (388.801 us; speedup 1.0000x reference)
//
#include <hip/hip_runtime.h>

#define IN_CH 128
#define OUT_CH 64
#define TILE_ROWS 32
#define ROWS_PER_WAVE 8

#define CSHIFT 8                 // coarse bucket = 256 dst nodes
#define SSHIFT 5                 // sub bucket   = 32 dst nodes
#define SUB_NODES 32
#define BIN_EPT 8                // edges per thread in bin_edges

// ---- 1. coarse-bucket histogram (LDS-aggregated) ----
__global__ void bucket_hist(const int* __restrict__ dst, int* __restrict__ ccnt,
                            int E, int NC) {
    __shared__ int h[256];
    for (int i = threadIdx.x; i < NC; i += blockDim.x) h[i] = 0;
    __syncthreads();
    int e0 = blockIdx.x * (blockDim.x * BIN_EPT) + threadIdx.x;
#pragma unroll
    for (int k = 0; k < BIN_EPT; ++k) {
        int e = e0 + k * blockDim.x;
        if (e < E) atomicAdd(&h[dst[e] >> CSHIFT], 1);
    }
    __syncthreads();
    for (int i = threadIdx.x; i < NC; i += blockDim.x)
        if (h[i]) atomicAdd(&ccnt[i], h[i]);
}

// ---- 2. exclusive scan over NC (<=256) buckets; gctr = running append ptr ----
__global__ void bucket_scan(const int* __restrict__ ccnt, int* __restrict__ coff,
                            int* __restrict__ gctr, int NC) {
    __shared__ int s[256];
    int t = threadIdx.x;
    int v0 = (t < NC) ? ccnt[t] : 0;
    s[t] = v0;
    __syncthreads();
    for (int off = 1; off < 256; off <<= 1) {
        int v = (t >= off) ? s[t - off] : 0;
        __syncthreads();
        s[t] += v;
        __syncthreads();
    }
    if (t < NC) { int ex = s[t] - v0; coff[t] = ex; gctr[t] = ex; }
    if (t == 0) coff[NC] = s[255];   // == E
}

// ---- 3. bin edges into coarse buckets, packed (dst<<16)|src ----
// Per-block LDS counting sort: one global atomic per (block,bucket) reserves a
// dense run -> same-XCD full-line writes, no 17x amplification.
__global__ void bin_edges(const int* __restrict__ ei, int* __restrict__ gctr,
                          unsigned int* __restrict__ ebuf, int E, int NC) {
    __shared__ int cnt[256];
    __shared__ int gbase[256];
    for (int i = threadIdx.x; i < NC; i += blockDim.x) cnt[i] = 0;
    __syncthreads();

    unsigned int pk[BIN_EPT];
    int bk[BIN_EPT];
    int e0 = blockIdx.x * (blockDim.x * BIN_EPT) + threadIdx.x;
#pragma unroll
    for (int k = 0; k < BIN_EPT; ++k) {
        int e = e0 + k * blockDim.x;
        if (e < E) {
            int s = ei[e];
            int d = ei[E + e];
            pk[k] = ((unsigned int)d << 16) | (unsigned int)s;
            bk[k] = d >> CSHIFT;
            atomicAdd(&cnt[bk[k]], 1);
        } else bk[k] = -1;
    }
    __syncthreads();
    for (int i = threadIdx.x; i < NC; i += blockDim.x) {
        int c = cnt[i];
        gbase[i] = c ? atomicAdd(&gctr[i], c) : 0;
    }
    __syncthreads();
    for (int i = threadIdx.x; i < NC; i += blockDim.x) cnt[i] = 0;  // reuse as local offset
    __syncthreads();
#pragma unroll
    for (int k = 0; k < BIN_EPT; ++k) {
        if (bk[k] >= 0) {
            int o = atomicAdd(&cnt[bk[k]], 1);
            ebuf[gbase[bk[k]] + o] = pk[k];
        }
    }
}

// ---- 4. degree + dinv per 32-node sub-bucket (LDS counters, dense store) ----
__global__ void degree_dinv(const unsigned int* __restrict__ ebuf,
                            const int* __restrict__ coff,
                            float* __restrict__ dinv, int N) {
    __shared__ int cnt[SUB_NODES];
    const int n0 = blockIdx.x << SSHIFT;
    if (threadIdx.x < SUB_NODES) cnt[threadIdx.x] = 0;
    __syncthreads();
    const int cb = n0 >> CSHIFT;
    const int ebeg = coff[cb], eend = coff[cb + 1];
    for (int i = ebeg + threadIdx.x; i < eend; i += blockDim.x) {
        int rel = (int)(ebuf[i] >> 16) - n0;
        if ((unsigned)rel < SUB_NODES) atomicAdd(&cnt[rel], 1);
    }
    __syncthreads();
    int n = n0 + threadIdx.x;
    if (threadIdx.x < SUB_NODES && n < N)
        dinv[n] = rsqrtf((float)(cnt[threadIdx.x] + 1));   // +1 self-loop
}

// ---- 5. GEMM: y = (z @ W) * dinv[row]  (unchanged from round 4) ----
__global__ void gemm_zw(const float* __restrict__ z, const float* __restrict__ W,
                        const float* __restrict__ dinv, float* __restrict__ y, int N) {
    __shared__ float Ws[IN_CH * OUT_CH];      // 32 KB
    __shared__ float Zs[TILE_ROWS * IN_CH];   // 16 KB
    {
        const float4* W4 = (const float4*)W;
        float4* Ws4 = (float4*)Ws;
        for (int i = threadIdx.x; i < IN_CH * OUT_CH / 4; i += blockDim.x)
            Ws4[i] = W4[i];
    }
    const int col  = threadIdx.x & 63;
    const int warp = threadIdx.x >> 6;
    const int nTiles = (N + TILE_ROWS - 1) / TILE_ROWS;

    for (int t = blockIdx.x; t < nTiles; t += gridDim.x) {
        const int row0 = t * TILE_ROWS;
        const int nr = min(TILE_ROWS, N - row0);
        __syncthreads();
        {
            const float4* zt = (const float4*)(z + (size_t)row0 * IN_CH);
            float4* Zs4 = (float4*)Zs;
            const int n4 = nr * (IN_CH / 4);
            for (int i = threadIdx.x; i < n4; i += blockDim.x)
                Zs4[i] = zt[i];
        }
        __syncthreads();

        const int rbase = warp * ROWS_PER_WAVE;
        if (rbase >= nr) continue;
        const int nrw = min(ROWS_PER_WAVE, nr - rbase);

        if (nrw == ROWS_PER_WAVE) {
            float acc[ROWS_PER_WAVE];
#pragma unroll
            for (int r = 0; r < ROWS_PER_WAVE; ++r) acc[r] = 0.f;
#pragma unroll
            for (int k4 = 0; k4 < IN_CH / 4; ++k4) {
                float4 zv[ROWS_PER_WAVE];
#pragma unroll
                for (int r = 0; r < ROWS_PER_WAVE; ++r)
                    zv[r] = *(const float4*)&Zs[(rbase + r) * IN_CH + k4 * 4];
#pragma unroll
                for (int j = 0; j < 4; ++j) {
                    float w = Ws[(k4 * 4 + j) * OUT_CH + col];
#pragma unroll
                    for (int r = 0; r < ROWS_PER_WAVE; ++r)
                        acc[r] = fmaf(((const float*)&zv[r])[j], w, acc[r]);
                }
            }
#pragma unroll
            for (int r = 0; r < ROWS_PER_WAVE; ++r) {
                int row = row0 + rbase + r;
                y[(size_t)row * OUT_CH + col] = acc[r] * dinv[row];
            }
        } else {
            for (int r = 0; r < nrw; ++r) {
                int row = row0 + rbase + r;
                float a = 0.f;
                for (int k = 0; k < IN_CH; ++k)
                    a = fmaf(Zs[(rbase + r) * IN_CH + k], Ws[k * OUT_CH + col], a);
                y[(size_t)row * OUT_CH + col] = a * dinv[row];
            }
        }
    }
}

// ---- 6. aggregate: block owns 32 dst nodes; scan coarse-bucket edges,
//        ballot-filter, gather y[src], ds_add_f32 into LDS tile; fused epilogue ----
__global__ void accumulate(const unsigned int* __restrict__ ebuf,
                           const int* __restrict__ coff,
                           const float* __restrict__ y,
                           const float* __restrict__ dinv,
                           const float* __restrict__ b,
                           float* __restrict__ out, int N) {
    __shared__ float tile[SUB_NODES * OUT_CH];   // 8 KB
    const int n0 = blockIdx.x << SSHIFT;
    const int lane = threadIdx.x & 63;
    const int wid = threadIdx.x >> 6;

    for (int i = threadIdx.x; i < SUB_NODES * OUT_CH; i += blockDim.x)
        tile[i] = 0.f;
    __syncthreads();

    const int cb = n0 >> CSHIFT;
    const int ebeg = coff[cb], eend = coff[cb + 1];

    for (int base = ebeg + wid * 64; base < eend; base += 4 * 64) {
        int i = base + lane;
        unsigned int p = (i < eend) ? ebuf[i] : 0xFFFF0000u;   // sentinel: no match
        int rel = (int)(p >> 16) - n0;
        unsigned long long mask = __ballot((unsigned)rel < SUB_NODES);
        while (mask) {   // wave-uniform loop (mask identical across lanes)
            int l0 = __ffsll((unsigned long long)mask) - 1; mask &= mask - 1;
            unsigned int p0 = __shfl(p, l0);
            if (mask) {   // peel two per iteration -> 2 loads in flight
                int l1 = __ffsll((unsigned long long)mask) - 1; mask &= mask - 1;
                unsigned int p1 = __shfl(p, l1);
                float v0 = y[(size_t)(p0 & 0xFFFFu) * OUT_CH + lane];
                float v1 = y[(size_t)(p1 & 0xFFFFu) * OUT_CH + lane];
                atomicAdd(&tile[((p0 >> 16) - (unsigned)n0) * OUT_CH + lane], v0);
                atomicAdd(&tile[((p1 >> 16) - (unsigned)n0) * OUT_CH + lane], v1);
            } else {
                float v0 = y[(size_t)(p0 & 0xFFFFu) * OUT_CH + lane];
                atomicAdd(&tile[((p0 >> 16) - (unsigned)n0) * OUT_CH + lane], v0);
            }
        }
    }
    __syncthreads();

    float bias = b[lane];
    for (int n = wid; n < SUB_NODES; n += 4) {
        int node = n0 + n;
        if (node >= N) break;
        float di = dinv[node];
        float v = tile[n * OUT_CH + lane] + y[(size_t)node * OUT_CH + lane]; // + self-loop
        out[(size_t)node * OUT_CH + lane] = fmaxf(fmaf(v, di, bias), 0.f);
    }
}

extern "C" void kernel_launch(void* const* d_in, const int* in_sizes, int n_in,
                              void* d_out, int out_size, void* d_ws, size_t ws_size,
                              hipStream_t stream) {
    const float* z  = (const float*)d_in[0];
    const int*   ei = (const int*)d_in[1];     // int32 [2, E]
    const float* W  = (const float*)d_in[2];
    const float* b  = (const float*)d_in[3];
    float*       out = (float*)d_out;

    const int N = in_sizes[0] / IN_CH;        // 50000  (< 65536 -> 16-bit packable)
    const int E = in_sizes[1] / 2;            // 800000
    const int NC = (N + (1 << CSHIFT) - 1) >> CSHIFT;   // 196 coarse buckets
    const int NS = (N + SUB_NODES - 1) >> SSHIFT;       // 1563 sub buckets

    // ws layout: y [N*64 f] | ebuf [E u32] | dinv [N f] | ccnt [NC] | coff [NC+1] | gctr [NC]
    float*        y    = (float*)d_ws;
    unsigned int* ebuf = (unsigned int*)(y + (size_t)N * OUT_CH);
    float*        dinv = (float*)(ebuf + E);
    int*          ccnt = (int*)(dinv + N);
    int*          coff = ccnt + NC;
    int*          gctr = coff + NC + 1;

    hipMemsetAsync(ccnt, 0, (size_t)NC * sizeof(int), stream);

    const int binBlocks = (E + 256 * BIN_EPT - 1) / (256 * BIN_EPT);   // 391

    bucket_hist<<<binBlocks, 256, 0, stream>>>(ei + E, ccnt, E, NC);
    bucket_scan<<<1, 256, 0, stream>>>(ccnt, coff, gctr, NC);
    bin_edges  <<<binBlocks, 256, 0, stream>>>(ei, gctr, ebuf, E, NC);
    degree_dinv<<<NS, 256, 0, stream>>>(ebuf, coff, dinv, N);
    gemm_zw    <<<768, 256, 0, stream>>>(z, W, dinv, y, N);
    accumulate <<<NS, 256, 0, stream>>>(ebuf, coff, y, dinv, b, out, N);
}

// Round 7
// 120.153 us; speedup vs baseline: 3.2359x; 3.2359x over previous
//
#include <hip/hip_runtime.h>

#define IN_CH 128
#define OUT_CH 64
#define TILE_ROWS 32
#define ROWS_PER_WAVE 8

#define CSHIFT 8                 // coarse bucket = 256 dst nodes
#define BIN_EPT 8                // edges per thread in binning kernels

// ---- 1. coarse-bucket histogram (LDS-aggregated) ----
__global__ void bucket_hist(const int* __restrict__ dst, int* __restrict__ ccnt,
                            int E, int NC) {
    __shared__ int h[256];
    for (int i = threadIdx.x; i < NC; i += blockDim.x) h[i] = 0;
    __syncthreads();
    int e0 = blockIdx.x * (blockDim.x * BIN_EPT) + threadIdx.x;
#pragma unroll
    for (int k = 0; k < BIN_EPT; ++k) {
        int e = e0 + k * blockDim.x;
        if (e < E) atomicAdd(&h[dst[e] >> CSHIFT], 1);
    }
    __syncthreads();
    for (int i = threadIdx.x; i < NC; i += blockDim.x)
        if (h[i]) atomicAdd(&ccnt[i], h[i]);
}

// ---- 2. exclusive scan over NC (<=256) buckets; gctr = running append ptr ----
__global__ void bucket_scan(const int* __restrict__ ccnt, int* __restrict__ coff,
                            int* __restrict__ gctr, int NC) {
    __shared__ int s[256];
    int t = threadIdx.x;
    int v0 = (t < NC) ? ccnt[t] : 0;
    s[t] = v0;
    __syncthreads();
    for (int off = 1; off < 256; off <<= 1) {
        int v = (t >= off) ? s[t - off] : 0;
        __syncthreads();
        s[t] += v;
        __syncthreads();
    }
    if (t < NC) { int ex = s[t] - v0; coff[t] = ex; gctr[t] = ex; }
    if (t == 0) coff[NC] = s[255];   // == E
}

// ---- 3. bin edges into coarse buckets, packed (dst<<16)|src ----
__global__ void bin_edges(const int* __restrict__ ei, int* __restrict__ gctr,
                          unsigned int* __restrict__ ebuf, int E, int NC) {
    __shared__ int cnt[256];
    __shared__ int gbase[256];
    for (int i = threadIdx.x; i < NC; i += blockDim.x) cnt[i] = 0;
    __syncthreads();

    unsigned int pk[BIN_EPT];
    int bk[BIN_EPT];
    int e0 = blockIdx.x * (blockDim.x * BIN_EPT) + threadIdx.x;
#pragma unroll
    for (int k = 0; k < BIN_EPT; ++k) {
        int e = e0 + k * blockDim.x;
        if (e < E) {
            int s = ei[e];
            int d = ei[E + e];
            pk[k] = ((unsigned int)d << 16) | (unsigned int)s;
            bk[k] = d >> CSHIFT;
            atomicAdd(&cnt[bk[k]], 1);
        } else bk[k] = -1;
    }
    __syncthreads();
    for (int i = threadIdx.x; i < NC; i += blockDim.x) {
        int c = cnt[i];
        gbase[i] = c ? atomicAdd(&gctr[i], c) : 0;
    }
    __syncthreads();
    for (int i = threadIdx.x; i < NC; i += blockDim.x) cnt[i] = 0;  // reuse as local cursor
    __syncthreads();
#pragma unroll
    for (int k = 0; k < BIN_EPT; ++k) {
        if (bk[k] >= 0) {
            int o = atomicAdd(&cnt[bk[k]], 1);
            ebuf[gbase[bk[k]] + o] = pk[k];
        }
    }
}

// ---- 4. per-bucket exact counting sort: col16 (src by dst), rowptr, dinv ----
// One block per coarse bucket. Writes land in a 16 KB contiguous, L2-resident
// region -> no write amplification. Also produces degree (-> dinv) densely.
__global__ void sort_bucket(const unsigned int* __restrict__ ebuf,
                            const int* __restrict__ coff,
                            unsigned short* __restrict__ col,
                            int* __restrict__ rowptr, float* __restrict__ dinv,
                            int N, int NC, int E) {
    __shared__ int cnt[256];
    __shared__ int off[256];
    const int b = blockIdx.x;
    const int n0 = b << CSHIFT;
    cnt[threadIdx.x] = 0;
    __syncthreads();

    const int ebeg = coff[b], eend = coff[b + 1];
    for (int i = ebeg + threadIdx.x; i < eend; i += 256)
        atomicAdd(&cnt[(ebuf[i] >> 16) - n0], 1);
    __syncthreads();

    const int c = cnt[threadIdx.x];
    const int node = n0 + threadIdx.x;
    if (node < N) dinv[node] = rsqrtf((float)(c + 1));   // +1 self-loop

    off[threadIdx.x] = c;
    __syncthreads();
    for (int o = 1; o < 256; o <<= 1) {
        int v = (threadIdx.x >= o) ? off[threadIdx.x - o] : 0;
        __syncthreads();
        off[threadIdx.x] += v;
        __syncthreads();
    }
    const int ex = off[threadIdx.x] - c;      // exclusive within-bucket offset
    if (node < N) rowptr[node] = ebeg + ex;
    if (b == NC - 1 && threadIdx.x == 0) rowptr[N] = E;

    cnt[threadIdx.x] = ex;                    // cursors
    __syncthreads();
    for (int i = ebeg + threadIdx.x; i < eend; i += 256) {
        unsigned int p = ebuf[i];
        int rel = (int)(p >> 16) - n0;
        int slot = atomicAdd(&cnt[rel], 1);
        col[ebeg + slot] = (unsigned short)(p & 0xFFFFu);
    }
}

// ---- 5. GEMM: y = (z @ W) * dinv[row]  (round-4 structure, proven) ----
__global__ void gemm_zw(const float* __restrict__ z, const float* __restrict__ W,
                        const float* __restrict__ dinv, float* __restrict__ y, int N) {
    __shared__ float Ws[IN_CH * OUT_CH];      // 32 KB
    __shared__ float Zs[TILE_ROWS * IN_CH];   // 16 KB
    {
        const float4* W4 = (const float4*)W;
        float4* Ws4 = (float4*)Ws;
        for (int i = threadIdx.x; i < IN_CH * OUT_CH / 4; i += blockDim.x)
            Ws4[i] = W4[i];
    }
    const int col  = threadIdx.x & 63;
    const int warp = threadIdx.x >> 6;
    const int nTiles = (N + TILE_ROWS - 1) / TILE_ROWS;

    for (int t = blockIdx.x; t < nTiles; t += gridDim.x) {
        const int row0 = t * TILE_ROWS;
        const int nr = min(TILE_ROWS, N - row0);
        __syncthreads();
        {
            const float4* zt = (const float4*)(z + (size_t)row0 * IN_CH);
            float4* Zs4 = (float4*)Zs;
            const int n4 = nr * (IN_CH / 4);
            for (int i = threadIdx.x; i < n4; i += blockDim.x)
                Zs4[i] = zt[i];
        }
        __syncthreads();

        const int rbase = warp * ROWS_PER_WAVE;
        if (rbase >= nr) continue;
        const int nrw = min(ROWS_PER_WAVE, nr - rbase);

        if (nrw == ROWS_PER_WAVE) {
            float acc[ROWS_PER_WAVE];
#pragma unroll
            for (int r = 0; r < ROWS_PER_WAVE; ++r) acc[r] = 0.f;
#pragma unroll
            for (int k4 = 0; k4 < IN_CH / 4; ++k4) {
                float4 zv[ROWS_PER_WAVE];
#pragma unroll
                for (int r = 0; r < ROWS_PER_WAVE; ++r)
                    zv[r] = *(const float4*)&Zs[(rbase + r) * IN_CH + k4 * 4];
#pragma unroll
                for (int j = 0; j < 4; ++j) {
                    float w = Ws[(k4 * 4 + j) * OUT_CH + col];
#pragma unroll
                    for (int r = 0; r < ROWS_PER_WAVE; ++r)
                        acc[r] = fmaf(((const float*)&zv[r])[j], w, acc[r]);
                }
            }
#pragma unroll
            for (int r = 0; r < ROWS_PER_WAVE; ++r) {
                int row = row0 + rbase + r;
                y[(size_t)row * OUT_CH + col] = acc[r] * dinv[row];
            }
        } else {
            for (int r = 0; r < nrw; ++r) {
                int row = row0 + rbase + r;
                float a = 0.f;
                for (int k = 0; k < IN_CH; ++k)
                    a = fmaf(Zs[(rbase + r) * IN_CH + k], Ws[k * OUT_CH + col], a);
                y[(size_t)row * OUT_CH + col] = a * dinv[row];
            }
        }
    }
}

// ---- 6. Gather: one wave per dst node; register accumulate; fused epilogue ----
__global__ void gather_nodes(const int* __restrict__ rowptr,
                             const unsigned short* __restrict__ col,
                             const float* __restrict__ y, const float* __restrict__ dinv,
                             const float* __restrict__ b, float* __restrict__ out, int N) {
    int d = blockIdx.x * (blockDim.x >> 6) + (threadIdx.x >> 6);
    if (d >= N) return;
    int lane = threadIdx.x & 63;
    int beg = rowptr[d], end = rowptr[d + 1];
    float acc = y[(size_t)d * OUT_CH + lane];    // self-loop term
    int j = beg;
    for (; j + 3 < end; j += 4) {
        int s0 = col[j], s1 = col[j + 1], s2 = col[j + 2], s3 = col[j + 3];
        float v0 = y[(size_t)s0 * OUT_CH + lane];
        float v1 = y[(size_t)s1 * OUT_CH + lane];
        float v2 = y[(size_t)s2 * OUT_CH + lane];
        float v3 = y[(size_t)s3 * OUT_CH + lane];
        acc += v0; acc += v1; acc += v2; acc += v3;
    }
    for (; j < end; ++j) acc += y[(size_t)col[j] * OUT_CH + lane];
    out[(size_t)d * OUT_CH + lane] = fmaxf(fmaf(acc, dinv[d], b[lane]), 0.f);
}

extern "C" void kernel_launch(void* const* d_in, const int* in_sizes, int n_in,
                              void* d_out, int out_size, void* d_ws, size_t ws_size,
                              hipStream_t stream) {
    const float* z  = (const float*)d_in[0];
    const int*   ei = (const int*)d_in[1];     // int32 [2, E]
    const float* W  = (const float*)d_in[2];
    const float* b  = (const float*)d_in[3];
    float*       out = (float*)d_out;

    const int N = in_sizes[0] / IN_CH;        // 50000 (< 65536 -> 16-bit packable)
    const int E = in_sizes[1] / 2;            // 800000
    const int NC = (N + (1 << CSHIFT) - 1) >> CSHIFT;   // 196 coarse buckets

    // ws layout: y [N*64 f] | col16 [E u16] | dinv [N f] | rowptr [N+1] | ccnt [NC] | coff [NC+1] | gctr [NC]
    // ebuf [E u32] ALIASES y: sort_bucket finishes reading ebuf before gemm writes y.
    float*          y    = (float*)d_ws;
    unsigned int*   ebuf = (unsigned int*)d_ws;
    unsigned short* col  = (unsigned short*)(y + (size_t)N * OUT_CH);
    float*          dinv = (float*)(col + E);
    int*            rowptr = (int*)(dinv + N);
    int*            ccnt = rowptr + N + 1;
    int*            coff = ccnt + NC;
    int*            gctr = coff + NC + 1;

    hipMemsetAsync(ccnt, 0, (size_t)NC * sizeof(int), stream);

    const int binBlocks = (E + 256 * BIN_EPT - 1) / (256 * BIN_EPT);   // 391

    bucket_hist<<<binBlocks, 256, 0, stream>>>(ei + E, ccnt, E, NC);
    bucket_scan<<<1, 256, 0, stream>>>(ccnt, coff, gctr, NC);
    bin_edges  <<<binBlocks, 256, 0, stream>>>(ei, gctr, ebuf, E, NC);
    sort_bucket<<<NC, 256, 0, stream>>>(ebuf, coff, col, rowptr, dinv, N, NC, E);
    gemm_zw    <<<768, 256, 0, stream>>>(z, W, dinv, y, N);
    gather_nodes<<<(N * 64 + 255) / 256, 256, 0, stream>>>(rowptr, col, y, dinv, b, out, N);
}